// Round 11
// baseline (284.661 us; speedup 1.0000x reference)
//
#include <hip/hip_runtime.h>
#include <hip/hip_bf16.h>

typedef __attribute__((ext_vector_type(8))) short bf16x8;
typedef __attribute__((ext_vector_type(4))) float f32x4;
typedef __attribute__((ext_vector_type(8))) unsigned short us8;
typedef __attribute__((ext_vector_type(4))) unsigned short us4;
typedef __attribute__((ext_vector_type(2))) unsigned short us2;

#define LOG2E 1.4426950408889634f

// Xl: stride 48 ushorts (24 dwords) — b128 reads spread 2 lanes/bank (free).
#define XL(r, c) ((r) * 48 + (c))
// H1: stride 256 ushorts, XOR swizzle of col bits 3-5 by row bits 0-2.
// b128 reads and us4 writes both land 2 lanes/bank (verified R10).
#define H1S(r, c) (((r) << 8) + (((c) ^ ((((r) & 1) << 5) | ((((r) >> 1) & 3) << 3)))))

__device__ __forceinline__ unsigned short f2bf(float f) {
  union { __hip_bfloat16 h; unsigned short u; } c;
  c.h = __float2bfloat16(f);
  return c.u;
}
__device__ __forceinline__ float bf2f(unsigned short u) {
  union { unsigned u; float f; } v; v.u = ((unsigned)u) << 16; return v.f;
}
__device__ __forceinline__ float fast_tanh(float x) {
  float e = __builtin_amdgcn_exp2f(x * (2.0f * LOG2E));     // e^(2x)
  return 1.0f - 2.0f * __builtin_amdgcn_rcpf(e + 1.0f);
}
__device__ __forceinline__ float fast_sig(float x) {
  return __builtin_amdgcn_rcpf(1.0f + __builtin_amdgcn_exp2f(-LOG2E * x));
}

// Permuted K-layout, K=48 real + zero tail (k48-63 via shared zero block).
// orig features: e2 0-11 | e3 12-29 | e4 30-37 | con 38-43. bias -> acc init.
// k0-11 e2 | k12-15 con c0-3 | k16-21 e3t0 | k22-23 con c4,c5 | k24-29 e3t1
// k30-31 z | k32-37 e3t2 | k38-39 z | k40-47 e4 | k48-63 z (shared block)
__device__ __forceinline__ int k2orig(int k) {
  if (k < 12) return k;
  if (k < 16) return 38 + (k - 12);
  if (k < 22) return 12 + (k - 16);
  if (k < 24) return 42 + (k - 22);
  if (k < 30) return 18 + (k - 24);
  if (k < 32) return -1;
  if (k < 38) return 24 + (k - 32);
  if (k < 40) return -1;
  if (k < 48) return 30 + (k - 40);
  return -1;
}

struct GatherRegs { int i0, i1, i2; float2 c01, c23; };

// 512-thread blocks (8 waves): 2 blocks/CU x 8 waves = 16 waves/CU = the HW
// cap at VGPR<=128 (m69) -> 4 waves/SIMD, 2x the latency hiding of all prior
// rounds (which were stuck at 2 waves/SIMD, ~40% stall). (512,4) = 4 waves/EU
// min -> VGPR cap 128. Persistent regs slimmed to ~100 (w1f 16, w2f 64,
// w3 packed bf16 4, b1f/b2f 16) so no spill (sentinel: WRITE_SIZE ~4.2MB).
__global__ __launch_bounds__(512, 4)
void mlp_fused(const float* __restrict__ con,
               const int* __restrict__ cat2,
               const int* __restrict__ cat3,
               const int* __restrict__ cat4,
               const float* __restrict__ emb2,
               const float* __restrict__ emb3,
               const float* __restrict__ emb4,
               const float* __restrict__ W1, const float* __restrict__ b1,
               const float* __restrict__ W2, const float* __restrict__ b2,
               const float* __restrict__ W3, const float* __restrict__ b3,
               float* __restrict__ out,
               int count)
{
  // ~40KB total -> 2 blocks/CU LDS-wise; wave cap (16/CU) is the binding one.
  __shared__ __align__(16) unsigned short embL[128];   // bf16 tables
  __shared__ __align__(16) unsigned short Xz[16];      // shared zero block
  __shared__ __align__(16) unsigned short Xl[64 * 48]; // X tile (single buf)
  __shared__ __align__(16) unsigned short H1[64 * 256];// h1 tile (single buf)
  __shared__ __align__(16) unsigned short Part[4][128];// bf16 L3 partials [fslice][row*2]

  const int t    = threadIdx.x;
  const int wv   = t >> 6;        // wave 0..7
  const int lane = t & 63;
  const int q    = lane >> 4;
  const int r16  = lane & 15;
  const int fs   = wv & 3;        // L2 feature slice
  const int rh   = wv >> 2;       // L2 row half
  const int tile0 = blockIdx.x * count;

  // ---- preamble: tables + zero block ---------------------------------------
  if (t < 24) embL[t] = f2bf(emb2[t]);                 // e2: 3 tbl x 2 x 4
  else if (t < 96) { int r = t - 24;                   // e3 rows padded 6->8
    embL[t] = ((r & 7) < 6) ? f2bf(emb3[(r >> 3) * 6 + (r & 7)]) : 0; }
  else if (t < 128) embL[t] = f2bf(emb4[t - 96]);      // e4: 4 x 8
  if (t < 16) Xz[t] = 0;

  // ---- persistent register fragments (per-wave slices) ---------------------
  bf16x8 w1f[2][2];               // L1: n = wv*32 + nf*16 + r16, K=64 padded
  #pragma unroll
  for (int nf = 0; nf < 2; ++nf)
    #pragma unroll
    for (int ks = 0; ks < 2; ++ks) {
      const int n = wv * 32 + nf * 16 + r16;
      bf16x8 w;
      #pragma unroll
      for (int j = 0; j < 8; ++j) {
        const int o = k2orig(ks * 32 + q * 8 + j);
        w[j] = (short)((o < 0) ? (unsigned short)0 : f2bf(W1[o * 256 + n]));
      }
      w1f[nf][ks] = w;
    }
  float b1f[2][4];                // L1 bias -> acc init
  #pragma unroll
  for (int nf = 0; nf < 2; ++nf)
    #pragma unroll
    for (int i = 0; i < 4; ++i)
      b1f[nf][i] = b1[wv * 32 + nf * 16 + q * 4 + i];
  bf16x8 w2f[2][8];               // L2: n = fs*32 + nf*16 + r16, K=256
  #pragma unroll
  for (int nf = 0; nf < 2; ++nf)
    #pragma unroll
    for (int ks = 0; ks < 8; ++ks) {
      const int n = fs * 32 + nf * 16 + r16;
      bf16x8 w;
      #pragma unroll
      for (int j = 0; j < 8; ++j)
        w[j] = (short)f2bf(W2[(ks * 32 + q * 8 + j) * 128 + n]);
      w2f[nf][ks] = w;
    }
  us2 w3p[2][4];                  // L3 weights packed bf16 (saves 12 VGPR)
  #pragma unroll
  for (int nf = 0; nf < 2; ++nf)
    #pragma unroll
    for (int i = 0; i < 4; ++i) {
      const int n = fs * 32 + nf * 16 + q * 4 + i;
      us2 p; p[0] = f2bf(W3[n * 2]); p[1] = f2bf(W3[n * 2 + 1]);
      w3p[nf][i] = p;
    }
  float b2f[2][4];
  #pragma unroll
  for (int nf = 0; nf < 2; ++nf)
    #pragma unroll
    for (int i = 0; i < 4; ++i)
      b2f[nf][i] = b2[fs * 32 + nf * 16 + q * 4 + i];
  const float b3x = b3[0], b3y = b3[1];

  // ---- helpers (8-wave field split for gather) -----------------------------
  auto gather_load = [&](int tile, GatherRegs& gr) {
    const int g = tile * 64 + lane;
    if      (wv == 0) { gr.i0 = cat2[g * 3]; gr.i1 = cat2[g * 3 + 1];
                        gr.i2 = cat2[g * 3 + 2]; }
    else if (wv == 1) { gr.c01 = *(const float2*)&con[g * 6];
                        gr.c23 = *(const float2*)&con[g * 6 + 2]; }
    else if (wv == 2) { gr.i0 = cat3[g * 3];
                        gr.c01 = *(const float2*)&con[g * 6 + 4]; }
    else if (wv == 3) { gr.i0 = cat3[g * 3 + 1]; }
    else if (wv == 4) { gr.i0 = cat3[g * 3 + 2]; }
    else if (wv == 5) { gr.i0 = cat4[g]; }
  };
  auto gather_write = [&](const GatherRegs& gr) {
    unsigned short* xr = &Xl[XL(lane, 0)];
    if (wv == 0) {
      *(us4*)&xr[0]  = *(const us4*)&embL[gr.i0 * 4];
      *(us4*)&xr[4]  = *(const us4*)&embL[8 + gr.i1 * 4];
      *(us4*)&xr[8]  = *(const us4*)&embL[16 + gr.i2 * 4];
    } else if (wv == 1) {
      us4 c; c[0] = f2bf(gr.c01.x); c[1] = f2bf(gr.c01.y);
             c[2] = f2bf(gr.c23.x); c[3] = f2bf(gr.c23.y);
      *(us4*)&xr[12] = c;
    } else if (wv == 2) {
      *(us8*)&xr[16] = *(const us8*)&embL[24 + gr.i0 * 8];   // e3t0 (+2 pad)
      us2 c; c[0] = f2bf(gr.c01.x); c[1] = f2bf(gr.c01.y);
      *(us2*)&xr[22] = c;                                    // c4,c5 over pad
    } else if (wv == 3) {
      *(us8*)&xr[24] = *(const us8*)&embL[48 + gr.i0 * 8];   // e3t1 (+z 30-31)
    } else if (wv == 4) {
      *(us8*)&xr[32] = *(const us8*)&embL[72 + gr.i0 * 8];   // e3t2 (+z 38-39)
    } else if (wv == 5) {
      *(us8*)&xr[40] = *(const us8*)&embL[96 + gr.i0 * 8];   // e4 k40-47
    }
  };
  auto layer1 = [&]() {            // Xl -> H1 (tanh); wave's 32-feature slice
    #pragma unroll
    for (int mf = 0; mf < 4; ++mf) {
      f32x4 acc[2];
      #pragma unroll
      for (int nf = 0; nf < 2; ++nf)
        #pragma unroll
        for (int i = 0; i < 4; ++i) acc[nf][i] = b1f[nf][i];
      bf16x8 xb0 = *(const bf16x8*)&Xl[XL(mf * 16 + r16, q * 8)];
      const unsigned short* s1 =
          (q < 2) ? &Xl[XL(mf * 16 + r16, 32 + q * 8)] : &Xz[0];
      bf16x8 xb1 = *(const bf16x8*)s1;  // q>=2 -> broadcast zeros (k48-63)
      #pragma unroll
      for (int nf = 0; nf < 2; ++nf)
        acc[nf] = __builtin_amdgcn_mfma_f32_16x16x32_bf16(
            w1f[nf][0], xb0, acc[nf], 0, 0, 0);
      #pragma unroll
      for (int nf = 0; nf < 2; ++nf)
        acc[nf] = __builtin_amdgcn_mfma_f32_16x16x32_bf16(
            w1f[nf][1], xb1, acc[nf], 0, 0, 0);
      #pragma unroll
      for (int nf = 0; nf < 2; ++nf) {
        us4 o;
        #pragma unroll
        for (int i = 0; i < 4; ++i) o[i] = f2bf(fast_tanh(acc[nf][i]));
        *(us4*)&H1[H1S(mf * 16 + r16, wv * 32 + nf * 16 + q * 4)] = o;
      }
    }
  };
  auto layer23 = [&]() {           // H1 -> tanh -> xW3 -> Part (fs, row-half rh)
    f32x4 acc[2][2];               // [nf][mf]
    #pragma unroll
    for (int nf = 0; nf < 2; ++nf)
      #pragma unroll
      for (int mf = 0; mf < 2; ++mf)
        #pragma unroll
        for (int i = 0; i < 4; ++i) acc[nf][mf][i] = b2f[nf][i];
    #pragma unroll
    for (int ks = 0; ks < 8; ++ks)
      #pragma unroll
      for (int mf = 0; mf < 2; ++mf) {
        bf16x8 hb = *(const bf16x8*)&H1[H1S(rh * 32 + mf * 16 + r16,
                                            ks * 32 + q * 8)];
        #pragma unroll
        for (int nf = 0; nf < 2; ++nf)
          acc[nf][mf] = __builtin_amdgcn_mfma_f32_16x16x32_bf16(
              w2f[nf][ks], hb, acc[nf][mf], 0, 0, 0);
      }
    #pragma unroll
    for (int mf = 0; mf < 2; ++mf) {
      float px = 0.f, py = 0.f;
      #pragma unroll
      for (int nf = 0; nf < 2; ++nf)
        #pragma unroll
        for (int i = 0; i < 4; ++i) {
          float tv = fast_tanh(acc[nf][mf][i]);
          px = fmaf(tv, bf2f(w3p[nf][i][0]), px);
          py = fmaf(tv, bf2f(w3p[nf][i][1]), py);
        }
      px += __shfl_xor(px, 16); py += __shfl_xor(py, 16);   // reduce over q
      px += __shfl_xor(px, 32); py += __shfl_xor(py, 32);
      if (q == 0) {                // bf16 partials (same scheme as R10)
        us2 pr; pr[0] = f2bf(px); pr[1] = f2bf(py);
        *(us2*)&Part[fs][(rh * 32 + mf * 16 + r16) * 2] = pr;
      }
    }
  };
  auto finalize = [&](int tile) {  // wave 7: sum 4 slice-partials, store
    if (wv == 7) {
      float sx = b3x, sy = b3y;
      #pragma unroll
      for (int f = 0; f < 4; ++f) {
        us2 pr = *(const us2*)&Part[f][lane * 2];
        sx += bf2f(pr[0]); sy += bf2f(pr[1]);
      }
      float2 o; o.x = fast_sig(sx); o.y = fast_sig(sy);
      *(float2*)&out[(tile * 64 + lane) * 2] = o;
    }
  };

  // ---- main loop: 2 barriers/tile, chunked contiguous tiles ----------------
  GatherRegs gr;
  __syncthreads();                 // embL/Xz ready before gather_write
  gather_load(tile0, gr);
  gather_write(gr);
  __syncthreads();
  layer1();                        // tile0: Xl -> H1
  __syncthreads();
  for (int j = 0; j < count; ++j) {
    const bool more = (j + 1 < count);
    if (more) gather_load(tile0 + j + 1, gr);  // HBM latency hides under L23
    layer23();                                 // reads H1(j), writes Part
    if (more) gather_write(gr);                // Xl <- tile j+1
    __syncthreads();
    finalize(tile0 + j);                       // reads Part
    if (more) layer1();                        // Xl -> H1(j+1)
    if (!more) break;
    __syncthreads();
  }
}

extern "C" void kernel_launch(void* const* d_in, const int* in_sizes, int n_in,
                              void* d_out, int out_size, void* d_ws, size_t ws_size,
                              hipStream_t stream) {
  (void)d_ws; (void)ws_size; (void)n_in; (void)out_size;
  const float* con  = (const float*)d_in[0];
  const int*   cat2 = (const int*)d_in[1];
  const int*   cat3 = (const int*)d_in[2];
  const int*   cat4 = (const int*)d_in[3];
  const float* emb2 = (const float*)d_in[4];
  const float* emb3 = (const float*)d_in[5];
  const float* emb4 = (const float*)d_in[6];
  const float* W1   = (const float*)d_in[7];
  const float* b1   = (const float*)d_in[8];
  const float* W2   = (const float*)d_in[9];
  const float* b2   = (const float*)d_in[10];
  const float* W3   = (const float*)d_in[11];
  const float* b3   = (const float*)d_in[12];
  float* out = (float*)d_out;

  const int rows  = in_sizes[0] / 6;        // B = 524288
  const int tiles = rows / 64;              // 8192
  const int nblocks = 512;                  // 2 blocks/CU (16 waves/CU cap)
  const int count = tiles / nblocks;        // 16 contiguous tiles per block

  hipLaunchKernelGGL(mlp_fused, dim3(nblocks), dim3(512), 0, stream,
                     con, cat2, cat3, cat4, emb2, emb3, emb4,
                     W1, b1, W2, b2, W3, b3, out, count);
}

// Round 12
// 105.698 us; speedup vs baseline: 2.6932x; 2.6932x over previous
//
#include <hip/hip_runtime.h>
#include <hip/hip_bf16.h>

typedef __attribute__((ext_vector_type(8))) short bf16x8;
typedef __attribute__((ext_vector_type(4))) float f32x4;
typedef __attribute__((ext_vector_type(8))) unsigned short us8;
typedef __attribute__((ext_vector_type(4))) unsigned short us4;
typedef __attribute__((ext_vector_type(2))) unsigned short us2;

#define LOG2E 1.4426950408889634f

// Xl: stride 48 ushorts (24 dwords) — b128 reads spread 2 lanes/bank (free).
#define XL(r, c) ((r) * 48 + (c))
// H1: stride 256 ushorts, XOR swizzle of col bits 3-5 by row bits 0-2.
// b128 reads and us4 writes both land 2 lanes/bank (verified R10).
#define H1S(r, c) (((r) << 8) + (((c) ^ ((((r) & 1) << 5) | ((((r) >> 1) & 3) << 3)))))

__device__ __forceinline__ unsigned short f2bf(float f) {
  union { __hip_bfloat16 h; unsigned short u; } c;
  c.h = __float2bfloat16(f);
  return c.u;
}
__device__ __forceinline__ float bf2f(unsigned short u) {
  union { unsigned u; float f; } v; v.u = ((unsigned)u) << 16; return v.f;
}
__device__ __forceinline__ float fast_tanh(float x) {
  float e = __builtin_amdgcn_exp2f(x * (2.0f * LOG2E));     // e^(2x)
  return 1.0f - 2.0f * __builtin_amdgcn_rcpf(e + 1.0f);
}
__device__ __forceinline__ float fast_sig(float x) {
  return __builtin_amdgcn_rcpf(1.0f + __builtin_amdgcn_exp2f(-LOG2E * x));
}

// Permuted K-layout, K=48 real + bias row k48 + zero tail.
// orig: e2 0-11 | e3 12-29 | e4 30-37 | con 38-43. k48 = bias (X=1.0).
// k0-11 e2 | k12-15 con c0-3 | k16-21 e3t0 | k22-23 con c4,c5 | k24-29 e3t1
// k30-31 z | k32-37 e3t2 | k38-39 z | k40-47 e4 | k48 bias | k49-63 z
__device__ __forceinline__ int k2orig(int k) {
  if (k < 12) return k;
  if (k < 16) return 38 + (k - 12);
  if (k < 22) return 12 + (k - 16);
  if (k < 24) return 42 + (k - 22);
  if (k < 30) return 18 + (k - 24);
  if (k < 32) return -1;
  if (k < 38) return 24 + (k - 32);
  if (k < 40) return -1;
  if (k < 48) return 30 + (k - 40);
  if (k == 48) return -2;                // bias row marker
  return -1;
}

struct GatherRegs { int i0, i1, i2; float2 c01, c23; };

// EMPIRICAL launch_bounds semantics on this toolchain (R4-R11 evidence):
// 2nd arg = min BLOCKS per CU (CUDA-style). VGPR cap = 512 / waves_per_SIMD:
//   (256,2)->8 w/CU->cap 256 (R6: 120, ok) ; (256,3)->12->cap 170 (spilled)
//   (512,4)->32 w/CU->cap 64 (R11: massive spill, 569MB FETCH)
// (512,2) -> 16 waves/CU = 4/SIMD -> cap 128. Persistent regs ~94 here.
__global__ __launch_bounds__(512, 2)
void mlp_fused(const float* __restrict__ con,
               const int* __restrict__ cat2,
               const int* __restrict__ cat3,
               const int* __restrict__ cat4,
               const float* __restrict__ emb2,
               const float* __restrict__ emb3,
               const float* __restrict__ emb4,
               const float* __restrict__ W1, const float* __restrict__ b1,
               const float* __restrict__ W2, const float* __restrict__ b2,
               const float* __restrict__ W3, const float* __restrict__ b3,
               float* __restrict__ out,
               int count)
{
  // ~40.3KB -> 2 blocks/CU LDS-wise; 16-wave cap is the binding resource.
  __shared__ __align__(16) unsigned short embL[128];   // bf16 tables
  __shared__ __align__(16) unsigned short Xz[16];      // zero block (k56-63)
  __shared__ __align__(16) unsigned short Xc[16];      // [1,0,..] (k48-55)
  __shared__ __align__(16) unsigned short Xl[64 * 48]; // X tile
  __shared__ __align__(16) unsigned short H1[64 * 256];// h1 tile
  __shared__ __align__(16) unsigned short Part[4][128];// bf16 L3 partials

  const int t    = threadIdx.x;
  const int wv   = t >> 6;        // wave 0..7
  const int lane = t & 63;
  const int q    = lane >> 4;
  const int r16  = lane & 15;
  const int fs   = wv & 3;        // L2 feature slice
  const int rh   = wv >> 2;       // L2 row half
  const int tile0 = blockIdx.x * count;

  // ---- preamble: tables + const blocks -------------------------------------
  if (t < 24) embL[t] = f2bf(emb2[t]);                 // e2: 3 tbl x 2 x 4
  else if (t < 96) { int r = t - 24;                   // e3 rows padded 6->8
    embL[t] = ((r & 7) < 6) ? f2bf(emb3[(r >> 3) * 6 + (r & 7)]) : 0; }
  else if (t < 128) embL[t] = f2bf(emb4[t - 96]);      // e4: 4 x 8
  if (t < 16) { Xz[t] = 0; Xc[t] = (t == 0) ? 0x3f80 : 0; }

  // ---- persistent register fragments (per-wave slices, ~94 VGPR) -----------
  bf16x8 w1f[2][2];               // L1: n = wv*32 + nf*16 + r16, K=64 padded
  #pragma unroll
  for (int nf = 0; nf < 2; ++nf)
    #pragma unroll
    for (int ks = 0; ks < 2; ++ks) {
      const int n = wv * 32 + nf * 16 + r16;
      bf16x8 w;
      #pragma unroll
      for (int j = 0; j < 8; ++j) {
        const int o = k2orig(ks * 32 + q * 8 + j);
        w[j] = (short)((o == -2) ? f2bf(b1[n])
                     : (o < 0)   ? (unsigned short)0
                                 : f2bf(W1[o * 256 + n]));
      }
      w1f[nf][ks] = w;
    }
  bf16x8 w2f[2][8];               // L2: n = fs*32 + nf*16 + r16, K=256
  #pragma unroll
  for (int nf = 0; nf < 2; ++nf)
    #pragma unroll
    for (int ks = 0; ks < 8; ++ks) {
      const int n = fs * 32 + nf * 16 + r16;
      bf16x8 w;
      #pragma unroll
      for (int j = 0; j < 8; ++j)
        w[j] = (short)f2bf(W2[(ks * 32 + q * 8 + j) * 128 + n]);
      w2f[nf][ks] = w;
    }
  us2 w3p[2][4];                  // L3 weights packed bf16
  us2 b2p[2][2];                  // L2 bias packed bf16 (b2 is tiny; exact here)
  #pragma unroll
  for (int nf = 0; nf < 2; ++nf) {
    #pragma unroll
    for (int i = 0; i < 4; ++i) {
      const int n = fs * 32 + nf * 16 + q * 4 + i;
      us2 p; p[0] = f2bf(W3[n * 2]); p[1] = f2bf(W3[n * 2 + 1]);
      w3p[nf][i] = p;
    }
    #pragma unroll
    for (int h = 0; h < 2; ++h) {
      us2 p;
      p[0] = f2bf(b2[fs * 32 + nf * 16 + q * 4 + h * 2]);
      p[1] = f2bf(b2[fs * 32 + nf * 16 + q * 4 + h * 2 + 1]);
      b2p[nf][h] = p;
    }
  }
  const float b3x = b3[0], b3y = b3[1];

  // ---- helpers (8-wave field split for gather) -----------------------------
  auto gather_load = [&](int tile, GatherRegs& gr) {
    const int g = tile * 64 + lane;
    if      (wv == 0) { gr.i0 = cat2[g * 3]; gr.i1 = cat2[g * 3 + 1];
                        gr.i2 = cat2[g * 3 + 2]; }
    else if (wv == 1) { gr.c01 = *(const float2*)&con[g * 6];
                        gr.c23 = *(const float2*)&con[g * 6 + 2]; }
    else if (wv == 2) { gr.i0 = cat3[g * 3];
                        gr.c01 = *(const float2*)&con[g * 6 + 4]; }
    else if (wv == 3) { gr.i0 = cat3[g * 3 + 1]; }
    else if (wv == 4) { gr.i0 = cat3[g * 3 + 2]; }
    else if (wv == 5) { gr.i0 = cat4[g]; }
  };
  auto gather_write = [&](const GatherRegs& gr) {
    unsigned short* xr = &Xl[XL(lane, 0)];
    if (wv == 0) {
      *(us4*)&xr[0]  = *(const us4*)&embL[gr.i0 * 4];
      *(us4*)&xr[4]  = *(const us4*)&embL[8 + gr.i1 * 4];
      *(us4*)&xr[8]  = *(const us4*)&embL[16 + gr.i2 * 4];
    } else if (wv == 1) {
      us4 c; c[0] = f2bf(gr.c01.x); c[1] = f2bf(gr.c01.y);
             c[2] = f2bf(gr.c23.x); c[3] = f2bf(gr.c23.y);
      *(us4*)&xr[12] = c;
    } else if (wv == 2) {
      *(us8*)&xr[16] = *(const us8*)&embL[24 + gr.i0 * 8];   // e3t0 (+2 pad)
      us2 c; c[0] = f2bf(gr.c01.x); c[1] = f2bf(gr.c01.y);
      *(us2*)&xr[22] = c;                                    // c4,c5 over pad
    } else if (wv == 3) {
      *(us8*)&xr[24] = *(const us8*)&embL[48 + gr.i0 * 8];   // e3t1 (+z 30-31)
    } else if (wv == 4) {
      *(us8*)&xr[32] = *(const us8*)&embL[72 + gr.i0 * 8];   // e3t2 (+z 38-39)
    } else if (wv == 5) {
      *(us8*)&xr[40] = *(const us8*)&embL[96 + gr.i0 * 8];   // e4 k40-47
    }
  };
  auto layer1 = [&]() {            // Xl -> H1 (tanh); wave's 32-feature slice
    #pragma unroll
    for (int mf = 0; mf < 4; ++mf) {
      f32x4 acc[2];
      #pragma unroll
      for (int nf = 0; nf < 2; ++nf)
        #pragma unroll
        for (int i = 0; i < 4; ++i) acc[nf][i] = 0.f;     // bias via k48 row
      bf16x8 xb0 = *(const bf16x8*)&Xl[XL(mf * 16 + r16, q * 8)];
      const unsigned short* s1 =
          (q < 2) ? &Xl[XL(mf * 16 + r16, 32 + q * 8)]
                  : ((q == 2) ? &Xc[0] : &Xz[0]);          // k48-63: bias+zeros
      bf16x8 xb1 = *(const bf16x8*)s1;
      #pragma unroll
      for (int nf = 0; nf < 2; ++nf)
        acc[nf] = __builtin_amdgcn_mfma_f32_16x16x32_bf16(
            w1f[nf][0], xb0, acc[nf], 0, 0, 0);
      #pragma unroll
      for (int nf = 0; nf < 2; ++nf)
        acc[nf] = __builtin_amdgcn_mfma_f32_16x16x32_bf16(
            w1f[nf][1], xb1, acc[nf], 0, 0, 0);
      #pragma unroll
      for (int nf = 0; nf < 2; ++nf) {
        us4 o;
        #pragma unroll
        for (int i = 0; i < 4; ++i) o[i] = f2bf(fast_tanh(acc[nf][i]));
        *(us4*)&H1[H1S(mf * 16 + r16, wv * 32 + nf * 16 + q * 4)] = o;
      }
    }
  };
  auto layer23 = [&]() {           // H1 -> tanh -> xW3 -> Part; mf-outer (8 acc)
    #pragma unroll
    for (int mf = 0; mf < 2; ++mf) {
      f32x4 acc[2];
      #pragma unroll
      for (int nf = 0; nf < 2; ++nf)
        #pragma unroll
        for (int i = 0; i < 4; ++i) acc[nf][i] = bf2f(b2p[nf][i >> 1][i & 1]);
      #pragma unroll
      for (int ks = 0; ks < 8; ++ks) {
        bf16x8 hb = *(const bf16x8*)&H1[H1S(rh * 32 + mf * 16 + r16,
                                            ks * 32 + q * 8)];
        #pragma unroll
        for (int nf = 0; nf < 2; ++nf)
          acc[nf] = __builtin_amdgcn_mfma_f32_16x16x32_bf16(
              w2f[nf][ks], hb, acc[nf], 0, 0, 0);
      }
      float px = 0.f, py = 0.f;
      #pragma unroll
      for (int nf = 0; nf < 2; ++nf)
        #pragma unroll
        for (int i = 0; i < 4; ++i) {
          float tv = fast_tanh(acc[nf][i]);
          px = fmaf(tv, bf2f(w3p[nf][i][0]), px);
          py = fmaf(tv, bf2f(w3p[nf][i][1]), py);
        }
      px += __shfl_xor(px, 16); py += __shfl_xor(py, 16);   // reduce over q
      px += __shfl_xor(px, 32); py += __shfl_xor(py, 32);
      if (q == 0) {
        us2 pr; pr[0] = f2bf(px); pr[1] = f2bf(py);
        *(us2*)&Part[fs][(rh * 32 + mf * 16 + r16) * 2] = pr;
      }
    }
  };
  auto finalize = [&](int tile) {  // wave 7: sum 4 slice-partials, store
    if (wv == 7) {
      float sx = b3x, sy = b3y;
      #pragma unroll
      for (int f = 0; f < 4; ++f) {
        us2 pr = *(const us2*)&Part[f][lane * 2];
        sx += bf2f(pr[0]); sy += bf2f(pr[1]);
      }
      float2 o; o.x = fast_sig(sx); o.y = fast_sig(sy);
      *(float2*)&out[(tile * 64 + lane) * 2] = o;
    }
  };

  // ---- main loop: 2 barriers/tile, chunked contiguous tiles ----------------
  GatherRegs gr;
  __syncthreads();                 // embL/Xz/Xc ready before gather_write
  gather_load(tile0, gr);
  gather_write(gr);
  __syncthreads();
  layer1();                        // tile0: Xl -> H1
  __syncthreads();
  for (int j = 0; j < count; ++j) {
    const bool more = (j + 1 < count);
    if (more) gather_load(tile0 + j + 1, gr);  // HBM latency hides under L23
    layer23();                                 // reads H1(j), writes Part
    if (more) gather_write(gr);                // Xl <- tile j+1
    __syncthreads();
    finalize(tile0 + j);                       // reads Part
    if (more) layer1();                        // Xl -> H1(j+1)
    if (!more) break;
    __syncthreads();
  }
}

extern "C" void kernel_launch(void* const* d_in, const int* in_sizes, int n_in,
                              void* d_out, int out_size, void* d_ws, size_t ws_size,
                              hipStream_t stream) {
  (void)d_ws; (void)ws_size; (void)n_in; (void)out_size;
  const float* con  = (const float*)d_in[0];
  const int*   cat2 = (const int*)d_in[1];
  const int*   cat3 = (const int*)d_in[2];
  const int*   cat4 = (const int*)d_in[3];
  const float* emb2 = (const float*)d_in[4];
  const float* emb3 = (const float*)d_in[5];
  const float* emb4 = (const float*)d_in[6];
  const float* W1   = (const float*)d_in[7];
  const float* b1   = (const float*)d_in[8];
  const float* W2   = (const float*)d_in[9];
  const float* b2   = (const float*)d_in[10];
  const float* W3   = (const float*)d_in[11];
  const float* b3   = (const float*)d_in[12];
  float* out = (float*)d_out;

  const int rows  = in_sizes[0] / 6;        // B = 524288
  const int tiles = rows / 64;              // 8192
  const int nblocks = 512;                  // 2 blocks/CU (16 waves/CU)
  const int count = tiles / nblocks;        // 16 contiguous tiles per block

  hipLaunchKernelGGL(mlp_fused, dim3(nblocks), dim3(512), 0, stream,
                     con, cat2, cat3, cat4, emb2, emb3, emb4,
                     W1, b1, W2, b2, W3, b3, out, count);
}